// Round 10
// baseline (380.053 us; speedup 1.0000x reference)
//
#include <hip/hip_runtime.h>
#include <hip/hip_bf16.h>

typedef unsigned short u16;
typedef __attribute__((ext_vector_type(8))) short short8;   // 8 x bf16 (4 VGPR)
typedef __attribute__((ext_vector_type(4))) short s16x4;
typedef __attribute__((ext_vector_type(4))) float f32x4;

#define T_SEQ  4096
#define HEADS  16
#define HDIM   64
#define CDIM   1024
#define MDIM   8192              // B*T
#define HSZ    (T_SEQ * HDIM)    // elems per (b,h) head-plane
#define SEC    8388608           // elems per qkv section = B*T*C

__device__ __forceinline__ u16 f2bf(float f) {
    __hip_bfloat16 h = __float2bfloat16(f);
    u16 u; __builtin_memcpy(&u, &h, 2);
    return u;
}
__device__ __forceinline__ float bf2f(u16 u) {
    unsigned int x = ((unsigned int)u) << 16;
    float f; __builtin_memcpy(&f, &x, 4);
    return f;
}

// ---------------------------------------------------------------------------
// fp32 -> bf16 cast, 4 elems/thread.
// ---------------------------------------------------------------------------
__global__ __launch_bounds__(256) void cast_k(const float* __restrict__ in,
                                              u16* __restrict__ out, int n4) {
    const int i = blockIdx.x * 256 + threadIdx.x;
    if (i < n4) {
        f32x4 v = ((const f32x4*)in)[i];
        s16x4 o;
        #pragma unroll
        for (int j = 0; j < 4; ++j) o[j] = (short)f2bf(v[j]);
        ((s16x4*)out)[i] = o;
    }
}

// ---------------------------------------------------------------------------
// Batched transpose: out[z][c][r] = (bf16)in[z][r][c].  R,C multiples of 32.
// grid (C/32, R/32, Z), block (32,8)
// ---------------------------------------------------------------------------
template <int IN_F32>
__global__ __launch_bounds__(256) void transpose_k(const void* __restrict__ in_,
                                                   u16* __restrict__ out,
                                                   int R, int C) {
    __shared__ u16 tile[32][33];
    const size_t zoff = (size_t)blockIdx.z * R * C;
    const int c0 = blockIdx.x * 32, r0 = blockIdx.y * 32;
    const int tx = threadIdx.x, ty = threadIdx.y;
    #pragma unroll
    for (int i = ty; i < 32; i += 8) {
        const size_t idx = zoff + (size_t)(r0 + i) * C + c0 + tx;
        tile[i][tx] = IN_F32 ? f2bf(((const float*)in_)[idx])
                             : ((const u16*)in_)[idx];
    }
    __syncthreads();
    #pragma unroll
    for (int i = ty; i < 32; i += 8)
        out[zoff + (size_t)(c0 + i) * R + r0 + tx] = tile[tx][i];
}

// ---------------------------------------------------------------------------
// bf16 GEMM: C[m][n] = sum_k A[m][k] * Bt[n][k] + bias[n]   (bias fp32)
//   128x128 tile, BK=64, 4 waves (2x2), 16x16x32 MFMA, XOR-swizzled LDS.
// MODE 0: qkv epilogue -> q->qws (bf16, PRE-SCALED by 1/8); k/v -> outp fp32
// MODE 1: proj epilogue -> y row-major fp32
// grid (N/128, MDIM/128), block 256
// ---------------------------------------------------------------------------
template <int MODE>
__global__ __launch_bounds__(256) void gemm_k(const u16* __restrict__ A,
                                              const u16* __restrict__ Bt,
                                              const float* __restrict__ bias,
                                              float* __restrict__ outp,
                                              u16* __restrict__ qws, int K) {
    __shared__ unsigned char sA[16384];   // [128 rows][64 k] bf16, 128B rows
    __shared__ unsigned char sB[16384];
    const int tid  = threadIdx.x;
    const int lane = tid & 63;
    const int w = tid >> 6, wr = w >> 1, wc = w & 1;
    const int m0 = blockIdx.y * 128, n0 = blockIdx.x * 128;
    const int fr = lane & 15, fg = lane >> 4;

    f32x4 acc[4][4] = {};

    const int srow  = tid >> 1;
    const int scolb = (tid & 1) * 64;
    const u16* ga = A  + (size_t)(m0 + srow) * K + (tid & 1) * 32;
    const u16* gb = Bt + (size_t)(n0 + srow) * K + (tid & 1) * 32;
    unsigned char* wAr = sA + srow * 128;
    unsigned char* wBr = sB + srow * 128;
    const int swz  = (srow & 7) << 4;
    const int rswz = (fr & 7) << 4;

    const int nk = K >> 6;
    for (int kt = 0; kt < nk; ++kt) {
        short8 va0 = *(const short8*)(ga + 0);
        short8 va1 = *(const short8*)(ga + 8);
        short8 va2 = *(const short8*)(ga + 16);
        short8 va3 = *(const short8*)(ga + 24);
        short8 vb0 = *(const short8*)(gb + 0);
        short8 vb1 = *(const short8*)(gb + 8);
        short8 vb2 = *(const short8*)(gb + 16);
        short8 vb3 = *(const short8*)(gb + 24);
        ga += 64; gb += 64;
        __syncthreads();
        *(short8*)(wAr + ((scolb +  0) ^ swz)) = va0;
        *(short8*)(wAr + ((scolb + 16) ^ swz)) = va1;
        *(short8*)(wAr + ((scolb + 32) ^ swz)) = va2;
        *(short8*)(wAr + ((scolb + 48) ^ swz)) = va3;
        *(short8*)(wBr + ((scolb +  0) ^ swz)) = vb0;
        *(short8*)(wBr + ((scolb + 16) ^ swz)) = vb1;
        *(short8*)(wBr + ((scolb + 32) ^ swz)) = vb2;
        *(short8*)(wBr + ((scolb + 48) ^ swz)) = vb3;
        __syncthreads();
        #pragma unroll
        for (int kk = 0; kk < 2; ++kk) {
            short8 af[4], bf[4];
            #pragma unroll
            for (int m = 0; m < 4; ++m)
                af[m] = *(const short8*)(sA + (wr*64 + m*16 + fr) * 128 +
                                         ((kk*64 + fg*16) ^ rswz));
            #pragma unroll
            for (int n = 0; n < 4; ++n)
                bf[n] = *(const short8*)(sB + (wc*64 + n*16 + fr) * 128 +
                                         ((kk*64 + fg*16) ^ rswz));
            #pragma unroll
            for (int m = 0; m < 4; ++m)
                #pragma unroll
                for (int n = 0; n < 4; ++n)
                    acc[m][n] = __builtin_amdgcn_mfma_f32_16x16x32_bf16(
                        af[m], bf[n], acc[m][n], 0, 0, 0);
        }
    }

    // epilogue: C/D layout col = lane&15, row = (lane>>4)*4 + reg  [m89]
    #pragma unroll
    for (int n = 0; n < 4; ++n) {
        const int gn = n0 + wc*64 + n*16 + fr;
        const float bn = bias[gn];
        if (MODE == 0) {
            const int s = gn >> 10;               // 0=q 1=k 2=v
            const int c = gn & 1023;
            const int h = c >> 6, d = c & 63;
            if (s == 0) {
                #pragma unroll
                for (int m = 0; m < 4; ++m)
                    #pragma unroll
                    for (int r = 0; r < 4; ++r) {
                        const int gm = m0 + wr*64 + m*16 + fg*4 + r;
                        const int b = gm >> 12, t = gm & 4095;
                        // pre-scale q by 1/sqrt(HD)=0.125 (q_ws is attn-private)
                        qws[(size_t)((b << 4) + h) * HSZ + (size_t)t * HDIM + d] =
                            f2bf((acc[m][n][r] + bn) * 0.125f);
                    }
            } else {
                float* fdst = outp + (size_t)s * SEC;
                #pragma unroll
                for (int m = 0; m < 4; ++m)
                    #pragma unroll
                    for (int r = 0; r < 4; ++r) {
                        const int gm = m0 + wr*64 + m*16 + fg*4 + r;
                        const int b = gm >> 12, t = gm & 4095;
                        fdst[(size_t)((b << 4) + h) * HSZ + (size_t)t * HDIM + d] =
                            acc[m][n][r] + bn;
                    }
            }
        } else {
            #pragma unroll
            for (int m = 0; m < 4; ++m)
                #pragma unroll
                for (int r = 0; r < 4; ++r) {
                    const int gm = m0 + wr*64 + m*16 + fg*4 + r;
                    outp[(size_t)gm * CDIM + gn] = acc[m][n][r] + bn;
                }
        }
    }
}

// ---------------------------------------------------------------------------
// Per-tile attention work for one q-block (16 rows/wave x 32 keys).
// Q is PRE-SCALED by 0.125. Caller guarantees kb2 <= q0+15 (not fully masked)
// and that sK/sV hold tile kb2. sPq = this wave's P buffer for this q-block.
// ---------------------------------------------------------------------------
__device__ __forceinline__ void attn_tile(
    const unsigned char* sK, const unsigned char* sV, unsigned char* sPq,
    short8 qf0, short8 qf1, int q0, int kb2,
    f32x4 (&o)[4], float (&mrow)[4], float (&srow)[4],
    int fr, int fg, int rswzK, int rswzP, int rswzV)
{
    // S = Q K^T (16 q x 32 key), two 16-key halves
    short8 kf0a = *(const short8*)(sK + fr * 128 + ((fg*16) ^ rswzK));
    short8 kf0b = *(const short8*)(sK + fr * 128 + ((64 + fg*16) ^ rswzK));
    short8 kf1a = *(const short8*)(sK + (16 + fr) * 128 + ((fg*16) ^ rswzK));
    short8 kf1b = *(const short8*)(sK + (16 + fr) * 128 + ((64 + fg*16) ^ rswzK));
    f32x4 z0 = {0.f, 0.f, 0.f, 0.f}, z1 = {0.f, 0.f, 0.f, 0.f};
    __builtin_amdgcn_s_setprio(1);
    z0 = __builtin_amdgcn_mfma_f32_16x16x32_bf16(qf0, kf0a, z0, 0, 0, 0);
    z0 = __builtin_amdgcn_mfma_f32_16x16x32_bf16(qf1, kf0b, z0, 0, 0, 0);
    z1 = __builtin_amdgcn_mfma_f32_16x16x32_bf16(qf0, kf1a, z1, 0, 0, 0);
    z1 = __builtin_amdgcn_mfma_f32_16x16x32_bf16(qf1, kf1b, z1, 0, 0, 0);
    __builtin_amdgcn_s_setprio(0);

    const bool full = (kb2 + 31 <= q0);   // wave-uniform: no masking needed
    #pragma unroll
    for (int r = 0; r < 4; ++r) {
        const int qg = q0 + fg * 4 + r;
        float s0 = z0[r], s1 = z1[r];
        if (!full) {
            s0 = (kb2 + fr      <= qg) ? s0 : -1e30f;
            s1 = (kb2 + 16 + fr <= qg) ? s1 : -1e30f;
        }
        // ballot-gated defer-max: reduce+rescale only when a lane in this
        // row's 16-group exceeds mrow+8 (p stays bounded by e^8).
        const float mx2 = fmaxf(s0, s1);
        const unsigned long long bb = __ballot(mx2 > mrow[r] + 8.f);
        if ((bb >> (fg * 16)) & 0xFFFFull) {
            float mx = mx2;
            mx = fmaxf(mx, __shfl_xor(mx, 1, 64));
            mx = fmaxf(mx, __shfl_xor(mx, 2, 64));
            mx = fmaxf(mx, __shfl_xor(mx, 4, 64));
            mx = fmaxf(mx, __shfl_xor(mx, 8, 64));
            const float sf = __expf(mrow[r] - mx);  // -1e30 start -> sf=0
            srow[r] *= sf;
            #pragma unroll
            for (int db = 0; db < 4; ++db) o[db][r] *= sf;
            mrow[r] = mx;
        }
        const float p0 = __expf(s0 - mrow[r]);
        const float p1 = __expf(s1 - mrow[r]);
        srow[r] += p0 + p1;
        const int prow = fg * 4 + r;
        const int sw = ((r ^ fg) & 3) << 4;
        *(u16*)(sPq + prow*64 + ((fr*2)      ^ sw)) = f2bf(p0);
        *(u16*)(sPq + prow*64 + ((32 + fr*2) ^ sw)) = f2bf(p1);
    }

    // sPq is per-wave: wave-local store->load ordering only (rule 18).
    asm volatile("s_waitcnt lgkmcnt(0)" ::: "memory");
    __builtin_amdgcn_sched_barrier(0);

    short8 pf = *(const short8*)(sPq + fr*64 + ((fg*16) ^ rswzP));
    __builtin_amdgcn_s_setprio(1);
    #pragma unroll
    for (int db = 0; db < 4; ++db) {
        short8 vf = *(const short8*)(sV + (db*16 + fr) * 64 + ((fg*16) ^ rswzV));
        o[db] = __builtin_amdgcn_mfma_f32_16x16x32_bf16(pf, vf, o[db], 0, 0, 0);
    }
    __builtin_amdgcn_s_setprio(0);
}

// ---------------------------------------------------------------------------
// Flash attention fwd (causal), bf16 MFMA, fp32 accum, XCD-locality remap,
// DUAL-QBLK: each block processes qlo=pair and qhi=63-pair CONCURRENTLY in
// one tile loop, sharing each staged K/V tile (25% fewer staging rounds).
//   q: (BH,T,64) bf16 pre-scaled   k: (BH,T,64) fp32   vt: (BH,64,T) bf16
//   att out: (B, T, H*64) bf16
// grid 1024 (=8 XCD x 4 bh x 32 pairs), block 256.
// ---------------------------------------------------------------------------
__global__ __launch_bounds__(256, 4) void attn_k(const u16* __restrict__ q,
                                                 const float* __restrict__ kk_,
                                                 const u16* __restrict__ vt,
                                                 u16* __restrict__ att) {
    __shared__ unsigned char sK[4096];   // [32 key][64 d]  128B rows
    __shared__ unsigned char sV[4096];   // [64 d][32 key]  64B rows (V^T tile)
    __shared__ unsigned char sP[8192];   // [wave][qsel][16 q][32 key]
    const int wg  = blockIdx.x;            // 0..1023
    const int xcd = wg & 7;
    const int i   = wg >> 3;               // 0..127
    const int bh  = xcd * 4 + (i >> 5);
    const int pair = i & 31;
    const int qlo = pair, qhi = 63 - pair;
    const int tid = threadIdx.x, lane = tid & 63, w = tid >> 6;
    const int fr = lane & 15, fg = lane >> 4;
    const size_t hbase = (size_t)bh * HSZ;

    const int krow = tid >> 3, kcolb = (tid & 7) * 16;
    const int swzK = (krow & 7) << 4;
    const int vrow = tid >> 2, vcolb = (tid & 3) * 16;
    const int swzV = (vrow & 3) << 4;
    const int rswzK = (fr & 7) << 4;
    const int rswzV = (fr & 3) << 4;
    const int rswzP = (((fr & 3) ^ ((fr >> 2) & 3)) << 4);

    const float* gk = kk_ + hbase + (size_t)krow * 64 + (tid & 7) * 8;  // fp32
    const u16*   gv = vt  + hbase + (size_t)vrow * T_SEQ + (tid & 3) * 8;
    const int b = bh >> 4, h = bh & 15;

    const int q0l = qlo * 64 + w * 16, q0h = qhi * 64 + w * 16;
    const short8 qf0l = *(const short8*)(q + hbase + (size_t)(q0l + fr) * 64 + fg * 8);
    const short8 qf1l = *(const short8*)(q + hbase + (size_t)(q0l + fr) * 64 + 32 + fg * 8);
    const short8 qf0h = *(const short8*)(q + hbase + (size_t)(q0h + fr) * 64 + fg * 8);
    const short8 qf1h = *(const short8*)(q + hbase + (size_t)(q0h + fr) * 64 + 32 + fg * 8);

    f32x4 oL[4] = {}, oH[4] = {};
    float mL[4] = {-1e30f, -1e30f, -1e30f, -1e30f};
    float mH[4] = {-1e30f, -1e30f, -1e30f, -1e30f};
    float sL[4] = {0.f, 0.f, 0.f, 0.f};
    float sH[4] = {0.f, 0.f, 0.f, 0.f};

    const int nktL = 2 * (qlo + 1);
    const int nktH = 2 * (qhi + 1);
    unsigned char* sPw = sP + w * 2048;

    for (int kt = 0; kt < nktH; ++kt) {
        f32x4 ka = *(const f32x4*)(gk + (size_t)kt * 2048);
        f32x4 kb = *(const f32x4*)(gk + (size_t)kt * 2048 + 4);
        short8 kv;
        #pragma unroll
        for (int j = 0; j < 4; ++j) {
            kv[j]     = (short)f2bf(ka[j]);
            kv[4 + j] = (short)f2bf(kb[j]);
        }
        short8 vv = *(const short8*)(gv + kt * 32);
        __syncthreads();
        *(short8*)(sK + krow * 128 + (kcolb ^ swzK)) = kv;
        *(short8*)(sV + vrow * 64  + (vcolb ^ swzV)) = vv;
        __syncthreads();

        const int kb2 = kt * 32;
        if (kb2 <= q0h + 15)                       // skip fully-masked (uniform)
            attn_tile(sK, sV, sPw + 1024, qf0h, qf1h, q0h, kb2,
                      oH, mH, sH, fr, fg, rswzK, rswzP, rswzV);
        if (kt < nktL && kb2 <= q0l + 15)
            attn_tile(sK, sV, sPw, qf0l, qf1l, q0l, kb2,
                      oL, mL, sL, fr, fg, rswzK, rswzP, rswzV);
    }

    // final softmax-denominator reduce + output, both q-blocks
    #pragma unroll
    for (int r = 0; r < 4; ++r) {
        float rsH = sH[r], rsL = sL[r];
        rsH += __shfl_xor(rsH, 1, 64);
        rsH += __shfl_xor(rsH, 2, 64);
        rsH += __shfl_xor(rsH, 4, 64);
        rsH += __shfl_xor(rsH, 8, 64);
        rsL += __shfl_xor(rsL, 1, 64);
        rsL += __shfl_xor(rsL, 2, 64);
        rsL += __shfl_xor(rsL, 4, 64);
        rsL += __shfl_xor(rsL, 8, 64);
        const float invH = 1.f / rsH;
        const float invL = 1.f / rsL;
        const int tH = q0h + fg * 4 + r;
        const int tL = q0l + fg * 4 + r;
        #pragma unroll
        for (int db = 0; db < 4; ++db) {
            att[(size_t)(b * T_SEQ + tH) * CDIM + h * 64 + db * 16 + fr] =
                f2bf(oH[db][r] * invH);
            att[(size_t)(b * T_SEQ + tL) * CDIM + h * 64 + db * 16 + fr] =
                f2bf(oL[db][r] * invL);
        }
    }
}

// ---------------------------------------------------------------------------
// Orchestration. Inputs fp32 (by size), outputs fp32 (y,k,v).
// Workspace (48 MiB, overlapped):
//   [ 0,16M)  q_ws bf16 (pre-scaled);  wTp overlays after attn
//   [16,32M)  x_bf -> vT bf16 after gemm0
//   [32,48M)  wTa -> attb bf16 after gemm0
// ---------------------------------------------------------------------------
extern "C" void kernel_launch(void* const* d_in, const int* in_sizes, int n_in,
                              void* d_out, int out_size, void* d_ws, size_t ws_size,
                              hipStream_t stream) {
    (void)out_size; (void)ws_size;
    const float *x = nullptr, *w_attn = nullptr, *b_attn = nullptr,
                *w_proj = nullptr, *b_proj = nullptr;
    for (int i = 0; i < n_in; ++i) {
        switch (in_sizes[i]) {
            case 8388608: x      = (const float*)d_in[i]; break;
            case 3145728: w_attn = (const float*)d_in[i]; break;
            case 3072:    b_attn = (const float*)d_in[i]; break;
            case 1048576: w_proj = (const float*)d_in[i]; break;
            case 1024:    b_proj = (const float*)d_in[i]; break;
        }
    }
    if (!x || !w_attn || !b_attn || !w_proj || !b_proj) return;

    float* out = (float*)d_out;
    unsigned char* ws = (unsigned char*)d_ws;

    u16* q_ws = (u16*)(ws);
    u16* wTp  = (u16*)(ws);
    u16* x_bf = (u16*)(ws + 16777216);
    u16* vT   = (u16*)(ws + 16777216);
    u16* wTa  = (u16*)(ws + 33554432);
    u16* attb = (u16*)(ws + 33554432);

    cast_k<<<8192, 256, 0, stream>>>(x, x_bf, 2097152);
    transpose_k<1><<<dim3(96, 32, 1), dim3(32, 8), 0, stream>>>(w_attn, wTa, 1024, 3072);
    gemm_k<0><<<dim3(24, 64), 256, 0, stream>>>(x_bf, wTa, b_attn, out, q_ws, 1024);
    transpose_k<1><<<dim3(2, 128, 32), dim3(32, 8), 0, stream>>>(out + 2 * (size_t)SEC, vT, 4096, 64);
    attn_k<<<1024, 256, 0, stream>>>(q_ws, out + SEC, vT, attb);
    transpose_k<1><<<dim3(32, 32, 1), dim3(32, 8), 0, stream>>>(w_proj, wTp, 1024, 1024);
    gemm_k<1><<<dim3(8, 64), 256, 0, stream>>>(attb, wTp, b_proj, out, nullptr, 1024);
}

// Round 11
// 350.814 us; speedup vs baseline: 1.0833x; 1.0833x over previous
//
#include <hip/hip_runtime.h>
#include <hip/hip_bf16.h>

typedef unsigned short u16;
typedef __attribute__((ext_vector_type(8))) short short8;   // 8 x bf16 (4 VGPR)
typedef __attribute__((ext_vector_type(4))) short s16x4;
typedef __attribute__((ext_vector_type(4))) float f32x4;

#define T_SEQ  4096
#define HEADS  16
#define HDIM   64
#define CDIM   1024
#define MDIM   8192              // B*T
#define HSZ    (T_SEQ * HDIM)    // elems per (b,h) head-plane
#define SEC    8388608           // elems per qkv section = B*T*C

__device__ __forceinline__ u16 f2bf(float f) {
    __hip_bfloat16 h = __float2bfloat16(f);
    u16 u; __builtin_memcpy(&u, &h, 2);
    return u;
}
__device__ __forceinline__ float bf2f(u16 u) {
    unsigned int x = ((unsigned int)u) << 16;
    float f; __builtin_memcpy(&f, &x, 4);
    return f;
}

// ---------------------------------------------------------------------------
// fp32 -> bf16 cast, 4 elems/thread.
// ---------------------------------------------------------------------------
__global__ __launch_bounds__(256) void cast_k(const float* __restrict__ in,
                                              u16* __restrict__ out, int n4) {
    const int i = blockIdx.x * 256 + threadIdx.x;
    if (i < n4) {
        f32x4 v = ((const f32x4*)in)[i];
        s16x4 o;
        #pragma unroll
        for (int j = 0; j < 4; ++j) o[j] = (short)f2bf(v[j]);
        ((s16x4*)out)[i] = o;
    }
}

// ---------------------------------------------------------------------------
// Batched transpose: out[z][c][r] = (bf16)in[z][r][c].  R,C multiples of 32.
// grid (C/32, R/32, Z), block (32,8)
// ---------------------------------------------------------------------------
template <int IN_F32>
__global__ __launch_bounds__(256) void transpose_k(const void* __restrict__ in_,
                                                   u16* __restrict__ out,
                                                   int R, int C) {
    __shared__ u16 tile[32][33];
    const size_t zoff = (size_t)blockIdx.z * R * C;
    const int c0 = blockIdx.x * 32, r0 = blockIdx.y * 32;
    const int tx = threadIdx.x, ty = threadIdx.y;
    #pragma unroll
    for (int i = ty; i < 32; i += 8) {
        const size_t idx = zoff + (size_t)(r0 + i) * C + c0 + tx;
        tile[i][tx] = IN_F32 ? f2bf(((const float*)in_)[idx])
                             : ((const u16*)in_)[idx];
    }
    __syncthreads();
    #pragma unroll
    for (int i = ty; i < 32; i += 8)
        out[zoff + (size_t)(c0 + i) * R + r0 + tx] = tile[tx][i];
}

// ---------------------------------------------------------------------------
// bf16 GEMM: C[m][n] = sum_k A[m][k] * Bt[n][k] + bias[n]   (bias fp32)
//   128x128 tile, BK=64, 4 waves (2x2), 16x16x32 MFMA, XOR-swizzled LDS.
// MODE 0: qkv epilogue -> q->qws (bf16, PRE-SCALED by 1/8); k/v -> outp fp32
// MODE 1: proj epilogue -> y row-major fp32
// grid (N/128, MDIM/128), block 256
// ---------------------------------------------------------------------------
template <int MODE>
__global__ __launch_bounds__(256) void gemm_k(const u16* __restrict__ A,
                                              const u16* __restrict__ Bt,
                                              const float* __restrict__ bias,
                                              float* __restrict__ outp,
                                              u16* __restrict__ qws, int K) {
    __shared__ unsigned char sA[16384];   // [128 rows][64 k] bf16, 128B rows
    __shared__ unsigned char sB[16384];
    const int tid  = threadIdx.x;
    const int lane = tid & 63;
    const int w = tid >> 6, wr = w >> 1, wc = w & 1;
    const int m0 = blockIdx.y * 128, n0 = blockIdx.x * 128;
    const int fr = lane & 15, fg = lane >> 4;

    f32x4 acc[4][4] = {};

    const int srow  = tid >> 1;
    const int scolb = (tid & 1) * 64;
    const u16* ga = A  + (size_t)(m0 + srow) * K + (tid & 1) * 32;
    const u16* gb = Bt + (size_t)(n0 + srow) * K + (tid & 1) * 32;
    unsigned char* wAr = sA + srow * 128;
    unsigned char* wBr = sB + srow * 128;
    const int swz  = (srow & 7) << 4;
    const int rswz = (fr & 7) << 4;

    const int nk = K >> 6;
    for (int kt = 0; kt < nk; ++kt) {
        short8 va0 = *(const short8*)(ga + 0);
        short8 va1 = *(const short8*)(ga + 8);
        short8 va2 = *(const short8*)(ga + 16);
        short8 va3 = *(const short8*)(ga + 24);
        short8 vb0 = *(const short8*)(gb + 0);
        short8 vb1 = *(const short8*)(gb + 8);
        short8 vb2 = *(const short8*)(gb + 16);
        short8 vb3 = *(const short8*)(gb + 24);
        ga += 64; gb += 64;
        __syncthreads();
        *(short8*)(wAr + ((scolb +  0) ^ swz)) = va0;
        *(short8*)(wAr + ((scolb + 16) ^ swz)) = va1;
        *(short8*)(wAr + ((scolb + 32) ^ swz)) = va2;
        *(short8*)(wAr + ((scolb + 48) ^ swz)) = va3;
        *(short8*)(wBr + ((scolb +  0) ^ swz)) = vb0;
        *(short8*)(wBr + ((scolb + 16) ^ swz)) = vb1;
        *(short8*)(wBr + ((scolb + 32) ^ swz)) = vb2;
        *(short8*)(wBr + ((scolb + 48) ^ swz)) = vb3;
        __syncthreads();
        #pragma unroll
        for (int kk = 0; kk < 2; ++kk) {
            short8 af[4], bf[4];
            #pragma unroll
            for (int m = 0; m < 4; ++m)
                af[m] = *(const short8*)(sA + (wr*64 + m*16 + fr) * 128 +
                                         ((kk*64 + fg*16) ^ rswz));
            #pragma unroll
            for (int n = 0; n < 4; ++n)
                bf[n] = *(const short8*)(sB + (wc*64 + n*16 + fr) * 128 +
                                         ((kk*64 + fg*16) ^ rswz));
            #pragma unroll
            for (int m = 0; m < 4; ++m)
                #pragma unroll
                for (int n = 0; n < 4; ++n)
                    acc[m][n] = __builtin_amdgcn_mfma_f32_16x16x32_bf16(
                        af[m], bf[n], acc[m][n], 0, 0, 0);
        }
    }

    // epilogue: C/D layout col = lane&15, row = (lane>>4)*4 + reg  [m89]
    #pragma unroll
    for (int n = 0; n < 4; ++n) {
        const int gn = n0 + wc*64 + n*16 + fr;
        const float bn = bias[gn];
        if (MODE == 0) {
            const int s = gn >> 10;               // 0=q 1=k 2=v
            const int c = gn & 1023;
            const int h = c >> 6, d = c & 63;
            if (s == 0) {
                #pragma unroll
                for (int m = 0; m < 4; ++m)
                    #pragma unroll
                    for (int r = 0; r < 4; ++r) {
                        const int gm = m0 + wr*64 + m*16 + fg*4 + r;
                        const int b = gm >> 12, t = gm & 4095;
                        // pre-scale q by 1/sqrt(HD)=0.125 (q_ws is attn-private)
                        qws[(size_t)((b << 4) + h) * HSZ + (size_t)t * HDIM + d] =
                            f2bf((acc[m][n][r] + bn) * 0.125f);
                    }
            } else {
                float* fdst = outp + (size_t)s * SEC;
                #pragma unroll
                for (int m = 0; m < 4; ++m)
                    #pragma unroll
                    for (int r = 0; r < 4; ++r) {
                        const int gm = m0 + wr*64 + m*16 + fg*4 + r;
                        const int b = gm >> 12, t = gm & 4095;
                        fdst[(size_t)((b << 4) + h) * HSZ + (size_t)t * HDIM + d] =
                            acc[m][n][r] + bn;
                    }
            }
        } else {
            #pragma unroll
            for (int m = 0; m < 4; ++m)
                #pragma unroll
                for (int r = 0; r < 4; ++r) {
                    const int gm = m0 + wr*64 + m*16 + fg*4 + r;
                    outp[(size_t)gm * CDIM + gn] = acc[m][n][r] + bn;
                }
        }
    }
}

// ---------------------------------------------------------------------------
// Flash attention fwd (causal), bf16 MFMA, fp32 accum, causal-balanced
// (sequential two-phase pairing, r9 structure), XCD-locality remap,
// DOUBLE-BUFFERED K/V LDS with ONE barrier per tile, load-early/write-late.
//   q: (BH,T,64) bf16 PRE-SCALED by 1/8   k: (BH,T,64) fp32   vt: (BH,64,T) bf16
//   att out: (B, T, H*64) bf16
// grid 1024 (=8 XCD x 4 bh x 32 pairs), block 256.
// ---------------------------------------------------------------------------
__global__ __launch_bounds__(256) void attn_k(const u16* __restrict__ q,
                                              const float* __restrict__ kk_,
                                              const u16* __restrict__ vt,
                                              u16* __restrict__ att) {
    __shared__ unsigned char sK[8192];   // 2 x [32 key][64 d] 128B rows
    __shared__ unsigned char sV[8192];   // 2 x [64 d][32 key] 64B rows
    __shared__ unsigned char sP[4096];   // per-wave [16 q][32 key] 1KB each
    const int wg  = blockIdx.x;            // 0..1023
    const int xcd = wg & 7;
    const int i   = wg >> 3;               // 0..127
    const int bh  = xcd * 4 + (i >> 5);
    const int pair = i & 31;
    const int tid = threadIdx.x, lane = tid & 63, w = tid >> 6;
    const int fr = lane & 15, fg = lane >> 4;
    const size_t hbase = (size_t)bh * HSZ;

    const int krow = tid >> 3, kcolb = (tid & 7) * 16;
    const int swzK = (krow & 7) << 4;
    const int vrow = tid >> 2, vcolb = (tid & 3) * 16;
    const int swzV = (vrow & 3) << 4;
    const int rswzK = (fr & 7) << 4;
    const int rswzV = (fr & 3) << 4;
    const int rswzP = (((fr & 3) ^ ((fr >> 2) & 3)) << 4);

    const float* gk = kk_ + hbase + (size_t)krow * 64 + (tid & 7) * 8;  // fp32
    const u16*   gv = vt  + hbase + (size_t)vrow * T_SEQ + (tid & 3) * 8;
    const int b = bh >> 4, h = bh & 15;

    unsigned char* sKw = sK + krow * 128 + (kcolb ^ swzK);
    unsigned char* sVw = sV + vrow * 64  + (vcolb ^ swzV);
    unsigned char* sPw = sP + w * 1024;

    #pragma unroll
    for (int ph = 0; ph < 2; ++ph) {
        const int qblk = ph ? 63 - pair : pair;
        const int q0 = qblk * 64 + w * 16;

        const short8 qf0 = *(const short8*)(q + hbase + (size_t)(q0 + fr) * 64 + fg * 8);
        const short8 qf1 = *(const short8*)(q + hbase + (size_t)(q0 + fr) * 64 + 32 + fg * 8);

        f32x4 o[4] = {};
        float mrow[4] = {-1e30f, -1e30f, -1e30f, -1e30f};
        float srow[4] = {0.f, 0.f, 0.f, 0.f};

        const int nkt = 2 * (qblk + 1);

        // ---- prologue: stage tile 0, prefetch tile 1 into registers ----
        f32x4 ka = *(const f32x4*)(gk);
        f32x4 kb = *(const f32x4*)(gk + 4);
        short8 vv = *(const short8*)(gv);
        __syncthreads();                 // protect previous phase's LDS reads
        {
            short8 kv;
            #pragma unroll
            for (int j = 0; j < 4; ++j) {
                kv[j]     = (short)f2bf(ka[j]);
                kv[4 + j] = (short)f2bf(kb[j]);
            }
            *(short8*)(sKw) = kv;
            *(short8*)(sVw) = vv;
        }
        ka = *(const f32x4*)(gk + 2048);
        kb = *(const f32x4*)(gk + 2048 + 4);
        vv = *(const short8*)(gv + 32);
        __syncthreads();                 // buf0 visible

        for (int kt = 0; kt < nkt; ++kt) {
            const int cur = (kt & 1) * 4096;
            const unsigned char* K = sK + cur;
            const unsigned char* V = sV + cur;

            // S = Q K^T (16 q x 32 key), two 16-key halves
            short8 kf0a = *(const short8*)(K + fr * 128 + ((fg*16) ^ rswzK));
            short8 kf0b = *(const short8*)(K + fr * 128 + ((64 + fg*16) ^ rswzK));
            short8 kf1a = *(const short8*)(K + (16 + fr) * 128 + ((fg*16) ^ rswzK));
            short8 kf1b = *(const short8*)(K + (16 + fr) * 128 + ((64 + fg*16) ^ rswzK));
            f32x4 z0 = {0.f, 0.f, 0.f, 0.f}, z1 = {0.f, 0.f, 0.f, 0.f};
            __builtin_amdgcn_s_setprio(1);
            z0 = __builtin_amdgcn_mfma_f32_16x16x32_bf16(qf0, kf0a, z0, 0, 0, 0);
            z0 = __builtin_amdgcn_mfma_f32_16x16x32_bf16(qf1, kf0b, z0, 0, 0, 0);
            z1 = __builtin_amdgcn_mfma_f32_16x16x32_bf16(qf0, kf1a, z1, 0, 0, 0);
            z1 = __builtin_amdgcn_mfma_f32_16x16x32_bf16(qf1, kf1b, z1, 0, 0, 0);
            __builtin_amdgcn_s_setprio(0);

            const int kb2 = kt * 32;
            const bool full = (kb2 + 31 <= q0);   // wave-uniform
            #pragma unroll
            for (int r = 0; r < 4; ++r) {
                const int qg = q0 + fg * 4 + r;
                float s0 = z0[r], s1 = z1[r];
                if (!full) {
                    s0 = (kb2 + fr      <= qg) ? s0 : -1e30f;
                    s1 = (kb2 + 16 + fr <= qg) ? s1 : -1e30f;
                }
                // ballot-gated defer-max: reduce+rescale only on real max bump
                const float mx2 = fmaxf(s0, s1);
                const unsigned long long bb = __ballot(mx2 > mrow[r] + 8.f);
                if ((bb >> (fg * 16)) & 0xFFFFull) {
                    float mx = mx2;
                    mx = fmaxf(mx, __shfl_xor(mx, 1, 64));
                    mx = fmaxf(mx, __shfl_xor(mx, 2, 64));
                    mx = fmaxf(mx, __shfl_xor(mx, 4, 64));
                    mx = fmaxf(mx, __shfl_xor(mx, 8, 64));
                    const float sf = __expf(mrow[r] - mx);  // -1e30 -> 0
                    srow[r] *= sf;
                    #pragma unroll
                    for (int db = 0; db < 4; ++db) o[db][r] *= sf;
                    mrow[r] = mx;
                }
                const float p0 = __expf(s0 - mrow[r]);   // bounded by e^8
                const float p1 = __expf(s1 - mrow[r]);
                srow[r] += p0 + p1;
                const int prow = fg * 4 + r;
                const int sw = ((r ^ fg) & 3) << 4;
                *(u16*)(sPw + prow*64 + ((fr*2)      ^ sw)) = f2bf(p0);
                *(u16*)(sPw + prow*64 + ((32 + fr*2) ^ sw)) = f2bf(p1);
            }

            // sP is per-wave: wave-local store->load ordering only (rule 18).
            asm volatile("s_waitcnt lgkmcnt(0)" ::: "memory");
            __builtin_amdgcn_sched_barrier(0);

            short8 pf = *(const short8*)(sPw + fr*64 + ((fg*16) ^ rswzP));
            __builtin_amdgcn_s_setprio(1);
            #pragma unroll
            for (int db = 0; db < 4; ++db) {
                short8 vf = *(const short8*)(V + (db*16 + fr) * 64 + ((fg*16) ^ rswzV));
                o[db] = __builtin_amdgcn_mfma_f32_16x16x32_bf16(pf, vf, o[db], 0, 0, 0);
            }
            __builtin_amdgcn_s_setprio(0);

            // ---- write-late: stage tile kt+1 (regs held), prefetch kt+2 ----
            if (kt + 1 < nkt) {
                const int nxt = ((kt + 1) & 1) * 4096;
                short8 kv;
                #pragma unroll
                for (int j = 0; j < 4; ++j) {
                    kv[j]     = (short)f2bf(ka[j]);
                    kv[4 + j] = (short)f2bf(kb[j]);
                }
                *(short8*)(sKw + nxt) = kv;
                *(short8*)(sVw + nxt) = vv;
                if (kt + 2 < nkt) {
                    ka = *(const f32x4*)(gk + (size_t)(kt + 2) * 2048);
                    kb = *(const f32x4*)(gk + (size_t)(kt + 2) * 2048 + 4);
                    vv = *(const short8*)(gv + (kt + 2) * 32);
                }
                __syncthreads();         // single barrier per tile
            }
        }

        // final softmax-denominator reduce + output
        #pragma unroll
        for (int r = 0; r < 4; ++r) {
            float rs = srow[r];
            rs += __shfl_xor(rs, 1, 64);
            rs += __shfl_xor(rs, 2, 64);
            rs += __shfl_xor(rs, 4, 64);
            rs += __shfl_xor(rs, 8, 64);
            const float inv = 1.f / rs;
            const int t = q0 + fg * 4 + r;
            #pragma unroll
            for (int db = 0; db < 4; ++db) {
                att[(size_t)(b * T_SEQ + t) * CDIM + h * 64 + db * 16 + fr] =
                    f2bf(o[db][r] * inv);
            }
        }
    }
}

// ---------------------------------------------------------------------------
// Orchestration. Inputs fp32 (by size), outputs fp32 (y,k,v).
// Workspace (48 MiB, overlapped):
//   [ 0,16M)  q_ws bf16 (pre-scaled);  wTp overlays after attn
//   [16,32M)  x_bf -> vT bf16 after gemm0
//   [32,48M)  wTa -> attb bf16 after gemm0
// ---------------------------------------------------------------------------
extern "C" void kernel_launch(void* const* d_in, const int* in_sizes, int n_in,
                              void* d_out, int out_size, void* d_ws, size_t ws_size,
                              hipStream_t stream) {
    (void)out_size; (void)ws_size;
    const float *x = nullptr, *w_attn = nullptr, *b_attn = nullptr,
                *w_proj = nullptr, *b_proj = nullptr;
    for (int i = 0; i < n_in; ++i) {
        switch (in_sizes[i]) {
            case 8388608: x      = (const float*)d_in[i]; break;
            case 3145728: w_attn = (const float*)d_in[i]; break;
            case 3072:    b_attn = (const float*)d_in[i]; break;
            case 1048576: w_proj = (const float*)d_in[i]; break;
            case 1024:    b_proj = (const float*)d_in[i]; break;
        }
    }
    if (!x || !w_attn || !b_attn || !w_proj || !b_proj) return;

    float* out = (float*)d_out;
    unsigned char* ws = (unsigned char*)d_ws;

    u16* q_ws = (u16*)(ws);
    u16* wTp  = (u16*)(ws);
    u16* x_bf = (u16*)(ws + 16777216);
    u16* vT   = (u16*)(ws + 16777216);
    u16* wTa  = (u16*)(ws + 33554432);
    u16* attb = (u16*)(ws + 33554432);

    cast_k<<<8192, 256, 0, stream>>>(x, x_bf, 2097152);
    transpose_k<1><<<dim3(96, 32, 1), dim3(32, 8), 0, stream>>>(w_attn, wTa, 1024, 3072);
    gemm_k<0><<<dim3(24, 64), 256, 0, stream>>>(x_bf, wTa, b_attn, out, q_ws, 1024);
    transpose_k<1><<<dim3(2, 128, 32), dim3(32, 8), 0, stream>>>(out + 2 * (size_t)SEC, vT, 4096, 64);
    attn_k<<<1024, 256, 0, stream>>>(q_ws, out + SEC, vT, attb);
    transpose_k<1><<<dim3(32, 32, 1), dim3(32, 8), 0, stream>>>(w_proj, wTp, 1024, 1024);
    gemm_k<1><<<dim3(8, 64), 256, 0, stream>>>(attb, wTp, b_proj, out, nullptr, 1024);
}